// Round 10
// baseline (166.375 us; speedup 1.0000x reference)
//
#include <hip/hip_runtime.h>
#include <hip/hip_bf16.h>

#define B_    8
#define C_    192
#define N_    3136
#define K_    9
#define OC    192
#define KDIM  384                 // 2*C
#define ROWS  (B_ * N_)           // 25088
#define BNK   (B_ * N_ * K_)      // 225792

typedef __hip_bfloat16 bf16;
using short8 = __attribute__((ext_vector_type(8))) short;
using us4    = __attribute__((ext_vector_type(4))) unsigned short;
using f32x4  = __attribute__((ext_vector_type(4))) float;

__device__ inline float bfbits2f(unsigned short u) {
    unsigned int x = ((unsigned int)u) << 16;
    return __builtin_bit_cast(float, x);
}
__device__ inline bf16 f2bf(float v) { return __float2bfloat16(v); }
__device__ inline unsigned short f2bfbits(float v) {
    bf16 t = __float2bfloat16(v);
    return *reinterpret_cast<unsigned short*>(&t);
}

// ---------------------------------------------------------------------------
// Kernel 1: transpose x,y (B,C,N) fp32 -> (B,N,C) bf16 (x into h's first half,
// y into yT). blockIdx.z==16 slice: W fp32->bf16 and stats zeroing.
// ---------------------------------------------------------------------------
__global__ void k_prep(const float* __restrict__ x, const float* __restrict__ y,
                       const float* __restrict__ W,
                       bf16* __restrict__ h, bf16* __restrict__ yT,
                       bf16* __restrict__ Wb, float* __restrict__ stats) {
    int tx = threadIdx.x, ty = threadIdx.y;
    int bz = blockIdx.z;
    if (bz == 16) {
        int flat = blockIdx.y * 98 + blockIdx.x;
        int t = ty * 32 + tx;
        if (flat < 288) {                       // 288*256 = 73728 = OC*KDIM
            int i = flat * 256 + t;
            Wb[i] = f2bf(W[i]);
        }
        if (flat == 0) stats[t] = 0.f;          // t in [0,256)
        if (flat == 1 && t < 128) stats[256 + t] = 0.f;
        return;
    }
    __shared__ float tile[32][33];
    int n0 = blockIdx.x * 32, c0 = blockIdx.y * 32;
    int b = bz >> 1, which = bz & 1;
    const float* src = which ? y : x;
#pragma unroll
    for (int i = 0; i < 4; i++) {
        int c = c0 + ty + i * 8;
        tile[ty + i * 8][tx] = src[((size_t)b * C_ + c) * N_ + n0 + tx];
    }
    __syncthreads();
    if (which == 0) {
#pragma unroll
        for (int i = 0; i < 4; i++) {
            int n = n0 + ty + i * 8;
            h[((size_t)b * N_ + n) * KDIM + c0 + tx] = f2bf(tile[tx][ty + i * 8]);
        }
    } else {
#pragma unroll
        for (int i = 0; i < 4; i++) {
            int n = n0 + ty + i * 8;
            yT[((size_t)b * N_ + n) * C_ + c0 + tx] = f2bf(tile[tx][ty + i * 8]);
        }
    }
}

// ---------------------------------------------------------------------------
// Kernel 2: per row (b,n): rel[c] = max_k ( y[b, j_k, c] - x[b, i_k, c] ),
// written to the second half of h's row. One wave per row; us4 (8B/lane)
// loads with 48 active lanes covering the 384B channel row.
// ---------------------------------------------------------------------------
__global__ void k_gather_rel(const int* __restrict__ ei, bf16* __restrict__ h,
                             const bf16* __restrict__ yT) {
    int wave = threadIdx.x >> 6;
    int lane = threadIdx.x & 63;
    int r = blockIdx.x * 4 + wave;           // global row = b*N + n
    int b = r / N_;

    const int* e0 = ei + (size_t)r * K_;               // edge_index[0] -> gathers y
    const int* e1 = ei + (size_t)BNK + (size_t)r * K_; // edge_index[1] -> gathers x
    int ej[K_], eii[K_];
#pragma unroll
    for (int k = 0; k < K_; k++) { ej[k] = e0[k]; eii[k] = e1[k]; }

    const us4* y4 = (const us4*)(yT + (size_t)b * N_ * C_);   // 48 u4 / row
    const us4* x4 = (const us4*)(h + (size_t)b * N_ * KDIM);  // 96 u4 / row

    if (lane < 48) {
        float m0 = -3.4e38f, m1 = -3.4e38f, m2 = -3.4e38f, m3 = -3.4e38f;
#pragma unroll
        for (int k = 0; k < K_; k++) {
            us4 vy = y4[(size_t)ej[k] * 48 + lane];
            us4 vx = x4[(size_t)eii[k] * 96 + lane];
            m0 = fmaxf(m0, bfbits2f(vy.x) - bfbits2f(vx.x));
            m1 = fmaxf(m1, bfbits2f(vy.y) - bfbits2f(vx.y));
            m2 = fmaxf(m2, bfbits2f(vy.z) - bfbits2f(vx.z));
            m3 = fmaxf(m3, bfbits2f(vy.w) - bfbits2f(vx.w));
        }
        us4 o;
        o.x = f2bfbits(m0); o.y = f2bfbits(m1);
        o.z = f2bfbits(m2); o.w = f2bfbits(m3);
        *((us4*)(h + (size_t)r * KDIM + C_) + lane) = o;
    }
}

// ---------------------------------------------------------------------------
// Kernel 3: GEMM pass 1 — per-channel sum / sumsq only (no output store).
// Block: 64 rows x 192 cols, 3 waves (each wave owns 64 o-cols), K=384.
// ---------------------------------------------------------------------------
__launch_bounds__(192)
__global__ void k_gemm_stats(const bf16* __restrict__ h, const bf16* __restrict__ Wb,
                             float* __restrict__ stats) {
    int tid = threadIdx.x;
    int wave = tid >> 6, lane = tid & 63;
    int fcol = lane & 15, fgrp = lane >> 4;
    int r0 = blockIdx.x * 64;
    int colbase = wave * 64;

    f32x4 acc[4][4] = {};

    for (int kk = 0; kk < 12; kk++) {
        short8 a[4], bb[4];
#pragma unroll
        for (int i = 0; i < 4; i++)
            a[i] = *reinterpret_cast<const short8*>(
                h + (size_t)(r0 + i * 16 + fcol) * KDIM + kk * 32 + fgrp * 8);
#pragma unroll
        for (int j = 0; j < 4; j++)
            bb[j] = *reinterpret_cast<const short8*>(
                Wb + (size_t)(colbase + j * 16 + fcol) * KDIM + kk * 32 + fgrp * 8);
#pragma unroll
        for (int i = 0; i < 4; i++)
#pragma unroll
            for (int j = 0; j < 4; j++)
                acc[i][j] = __builtin_amdgcn_mfma_f32_16x16x32_bf16(a[i], bb[j], acc[i][j], 0, 0, 0);
    }

#pragma unroll
    for (int j = 0; j < 4; j++) {
        int o = colbase + j * 16 + fcol;
        float s1 = 0.f, s2 = 0.f;
#pragma unroll
        for (int i = 0; i < 4; i++)
#pragma unroll
            for (int e = 0; e < 4; e++) {
                float v = acc[i][j][e];
                s1 += v;
                s2 += v * v;
            }
        s1 += __shfl_xor(s1, 16); s1 += __shfl_xor(s1, 32);
        s2 += __shfl_xor(s2, 16); s2 += __shfl_xor(s2, 32);
        if (fgrp == 0) {
            atomicAdd(&stats[o], s1);
            atomicAdd(&stats[OC + o], s2);
        }
    }
}

// ---------------------------------------------------------------------------
// Kernel 4: GEMM pass 2 (operand-swapped: A=W rows->D rows = o,
// B=h rows->D cols = n) + BN + exact GELU, storing out (b,o,n) coalesced.
// ---------------------------------------------------------------------------
__launch_bounds__(192)
__global__ void k_gemm_bn(const bf16* __restrict__ h, const bf16* __restrict__ Wb,
                          const float* __restrict__ stats,
                          const float* __restrict__ gamma, const float* __restrict__ beta,
                          float* __restrict__ out) {
    int tid = threadIdx.x;
    int wave = tid >> 6, lane = tid & 63;
    int fcol = lane & 15, fgrp = lane >> 4;
    int r0 = blockIdx.x * 64;            // 64 rows within one batch (3136 % 64 == 0)
    int b = r0 / N_;
    int n0 = r0 % N_;
    int colbase = wave * 64;

    f32x4 acc[4][4] = {};

    for (int kk = 0; kk < 12; kk++) {
        short8 wfr[4], hfr[4];
#pragma unroll
        for (int i = 0; i < 4; i++)
            wfr[i] = *reinterpret_cast<const short8*>(
                Wb + (size_t)(colbase + i * 16 + fcol) * KDIM + kk * 32 + fgrp * 8);
#pragma unroll
        for (int j = 0; j < 4; j++)
            hfr[j] = *reinterpret_cast<const short8*>(
                h + (size_t)(r0 + j * 16 + fcol) * KDIM + kk * 32 + fgrp * 8);
#pragma unroll
        for (int i = 0; i < 4; i++)
#pragma unroll
            for (int j = 0; j < 4; j++)
                acc[i][j] = __builtin_amdgcn_mfma_f32_16x16x32_bf16(wfr[i], hfr[j], acc[i][j], 0, 0, 0);
    }

    const float invc = 1.0f / (float)ROWS;
#pragma unroll
    for (int i = 0; i < 4; i++) {
#pragma unroll
        for (int e = 0; e < 4; e++) {
            int o = colbase + i * 16 + fgrp * 4 + e;   // D row
            float mean = stats[o] * invc;
            float var  = stats[OC + o] * invc - mean * mean;
            float is   = rsqrtf(var + 1e-5f);
            float sc = gamma[o] * is;
            float sh = beta[o] - mean * sc;
#pragma unroll
            for (int j = 0; j < 4; j++) {
                float z = acc[i][j][e] * sc + sh;
                float gl = 0.5f * z * (1.0f + erff(z * 0.70710678118654752f));
                out[((size_t)b * OC + o) * N_ + n0 + j * 16 + fcol] = gl;
            }
        }
    }
}

// ---------------------------------------------------------------------------
extern "C" void kernel_launch(void* const* d_in, const int* in_sizes, int n_in,
                              void* d_out, int out_size, void* d_ws, size_t ws_size,
                              hipStream_t stream) {
    const float* x     = (const float*)d_in[0];
    const float* y     = (const float*)d_in[1];
    const int*   ei    = (const int*)d_in[2];
    const float* W     = (const float*)d_in[3];
    const float* gamma = (const float*)d_in[4];
    const float* beta  = (const float*)d_in[5];
    float* out = (float*)d_out;

    char* ws = (char*)d_ws;
    // layout:
    //   h     : ROWS*384 bf16 = 19,267,584 B  (first half x, second half rel)
    //   yT    : ROWS*192 bf16 =  9,633,792 B
    //   Wb    : 192*384  bf16 =    147,456 B
    //   stats : 384 fp32      =      1,536 B
    bf16*  h     = (bf16*)(ws);
    bf16*  yT    = (bf16*)(ws + 19267584);
    bf16*  Wb    = (bf16*)(ws + 19267584 + 9633792);
    float* stats = (float*)(ws + 19267584 + 9633792 + 147456);

    dim3 bt(32, 8);
    k_prep<<<dim3(N_ / 32, C_ / 32, 2 * B_ + 1), bt, 0, stream>>>(x, y, W, h, yT, Wb, stats);
    k_gather_rel<<<ROWS / 4, 256, 0, stream>>>(ei, h, yT);
    k_gemm_stats<<<ROWS / 64, 192, 0, stream>>>(h, Wb, stats);
    k_gemm_bn<<<ROWS / 64, 192, 0, stream>>>(h, Wb, stats, gamma, beta, out);
}